// Round 1
// baseline (267.965 us; speedup 1.0000x reference)
//
#include <hip/hip_runtime.h>
#include <math.h>

#define NG 4096
#define NN 262144
#define D 128
#define M1 64
#define NH 8
#define GPB 8          // graphs per block (contiguous node range, batch sorted)
#define EPS 1e-6f

typedef __attribute__((ext_vector_type(8))) short short8;
typedef __attribute__((ext_vector_type(8))) unsigned char uchar8;
typedef __attribute__((ext_vector_type(4))) float f32x4;

__device__ inline float leaky(float x) { return x > 0.f ? x : 0.01f * x; }

// fp32 -> bf16 round-to-nearest-even
__device__ inline short f2bf(float f) {
  union { float f; unsigned u; } v; v.f = f;
  unsigned r = (v.u + 0x7fffu + ((v.u >> 16) & 1u)) >> 16;
  return (short)r;
}
__device__ inline float bf2f(short s) {
  union { unsigned u; float f; } v;
  v.u = ((unsigned)(unsigned short)s) << 16;
  return v.f;
}

// ---------------------------------------------------------------------------
// Prep: blocks 0..35 transpose W3 -> W3T[128,1024] bf16, W4 -> W4T[128,128];
// blocks 36..51: starts[g] = lower_bound(batch, g) (4096-way parallel binary
// search; batch is sorted), starts[NG] = NN.
// ---------------------------------------------------------------------------
__global__ __launch_bounds__(256) void k0b_prep(
    const float* __restrict__ W3, const float* __restrict__ W4,
    const int* __restrict__ batch,
    short* __restrict__ W3T, short* __restrict__ W4T,
    int* __restrict__ starts) {
  __shared__ float tile[64][65];
  int b = blockIdx.x, t = threadIdx.x;
  if (b >= 36) {
    int g = (b - 36) * 256 + t;
    int lo = 0, hi = NN;
    while (lo < hi) {
      int mid = (lo + hi) >> 1;
      if (batch[mid] < g) lo = mid + 1; else hi = mid;
    }
    starts[g] = lo;
    if (g == 0) starts[NG] = NN;
    return;
  }
  const float* src; short* dst; int kt, nt, tkl;
  if (b < 32) { src = W3; dst = W3T; kt = b >> 1; nt = b & 1; tkl = 1024; }
  else        { src = W4; dst = W4T; kt = (b - 32) >> 1; nt = (b - 32) & 1; tkl = 128; }

#pragma unroll
  for (int i = 0; i < 4; ++i) {
    int id = t + 256 * i;
    int r = id >> 4, c4 = (id & 15) * 4;
    float4 v = *(const float4*)(src + (size_t)(kt * 64 + r) * D + nt * 64 + c4);
    tile[r][c4 + 0] = v.x; tile[r][c4 + 1] = v.y;
    tile[r][c4 + 2] = v.z; tile[r][c4 + 3] = v.w;
  }
  __syncthreads();
  int n = t >> 2, kb = (t & 3) * 16;
  short8 p0, p1;
#pragma unroll
  for (int j = 0; j < 8; ++j) {
    p0[j] = f2bf(tile[kb + j][n]);
    p1[j] = f2bf(tile[kb + 8 + j][n]);
  }
  short* o = dst + (size_t)(nt * 64 + n) * tkl + kt * 64 + kb;
  *(short8*)o = p0;
  *(short8*)(o + 8) = p1;
}

// ---------------------------------------------------------------------------
// FUSED: one block owns graphs [G0, G0+8) = contiguous nodes [s0, s1).
// Per 128-node chunk: GEMM1 -> LN64 -> GEMM2 -> exp -> in-LDS segment sums
// (sL) + windowed aggregation MFMA accumulated into LDS agg (no global
// atomics). Epilogue: normalize, W3 GEMM -> LN128 -> W4 GEMM -> LN128 -> out.
// ---------------------------------------------------------------------------
__global__ __launch_bounds__(256, 2) void k_fused(
    const float* __restrict__ feat, const int* __restrict__ batch,
    const int* __restrict__ starts,
    const float* __restrict__ W1, const float* __restrict__ b1,
    const float* __restrict__ g1, const float* __restrict__ beta1,
    const float* __restrict__ W2, const float* __restrict__ b2,
    const short* __restrict__ W3T, const float* __restrict__ b3,
    const float* __restrict__ g3, const float* __restrict__ beta3,
    const short* __restrict__ W4T, const float* __restrict__ b4,
    const float* __restrict__ g4, const float* __restrict__ beta4,
    float* __restrict__ out) {
  __shared__ short W1T[M1][D + 8];          // 17408 B
  __shared__ short W2T[16][M1 + 8];         // 2304 B
  __shared__ short hb[128][72];             // 18432 B; overlays: attB, aL
  __shared__ float agg[GPB][NH][D + 4];     // 33792 B, +4 pad: 2-way banks max
  __shared__ float sL[GPB][NH];             // 256 B
  __shared__ unsigned char giL2[2][128];    // dbuf: no extra barrier per chunk
  __shared__ float red[4][2][16];           // 512 B
  __shared__ short hbuf2[16][136];          // 4352 B      total ~77.3 KB

  short (*attB)[136] = (short(*)[136])&hb[0][0];   // [h][node], 4-bank skew
  short (*aL)[1040] = (short(*)[1040])&hb[0][0];   // [gi][h*128+d] bf16

  int t = threadIdx.x;
  int G0 = blockIdx.x * GPB;
  int w = t >> 6, l = t & 63;
  int lr = l & 15, lq = l >> 4;

  // ---- one-time staging: W1T (transposed bf16), W2T; zero agg/sL
#pragma unroll
  for (int i = 0; i < 8; ++i) {
    int idx4 = t + 256 * i;
    int k = idx4 >> 4, j = (idx4 & 15) * 4;
    float4 wv = *(const float4*)(W1 + k * M1 + j);
    W1T[j + 0][k] = f2bf(wv.x);
    W1T[j + 1][k] = f2bf(wv.y);
    W1T[j + 2][k] = f2bf(wv.z);
    W1T[j + 3][k] = f2bf(wv.w);
  }
#pragma unroll
  for (int i = 0; i < 4; ++i) {
    int e = t * 4 + i;
    int hh = e >> 6, j = e & 63;
    W2T[hh][j] = (hh < NH) ? f2bf(W2[j * NH + hh]) : (short)0;
  }
  for (int i = t; i < GPB * NH * (D + 4); i += 256) (&agg[0][0][0])[i] = 0.f;
  if (t < GPB * NH) (&sL[0][0])[t] = 0.f;

  // per-lane constants hoisted out of the chunk loop
  float b1v[4], g1v[4], btv[4];
#pragma unroll
  for (int nt = 0; nt < 4; ++nt) {
    b1v[nt] = b1[nt * 16 + lr];
    g1v[nt] = g1[nt * 16 + lr];
    btv[nt] = beta1[nt * 16 + lr];
  }
  float b2v = b2[lr & 7];

  int s0 = starts[G0], s1 = starts[G0 + GPB];
  int nchunks = (s1 - s0 + 127) >> 7;

  for (int c = 0; c < nchunks; ++c) {
    int base = s0 + (c << 7);
    int nvalid = min(128, s1 - base);
    unsigned char* gi = giL2[c & 1];
    if (t < 128)
      gi[t] = (t < nvalid) ? (unsigned char)(batch[base + t] - G0)
                           : (unsigned char)255;  // tail sentinel: never matches

    // A-frags for GEMM1 (global only; overlaps barrier wait)
    short8 afr[2][4];
#pragma unroll
    for (int mt = 0; mt < 2; ++mt) {
      int node = base + w * 32 + mt * 16 + lr;
      node = node < NN ? node : NN - 1;   // tail clamp (masked later)
      const float* rp = feat + (size_t)node * D + lq * 8;
#pragma unroll
      for (int cc = 0; cc < 4; ++cc) {
        float4 x0 = *(const float4*)(rp + cc * 32);
        float4 x1 = *(const float4*)(rp + cc * 32 + 4);
        short8 a;
        a[0] = f2bf(x0.x); a[1] = f2bf(x0.y); a[2] = f2bf(x0.z); a[3] = f2bf(x0.w);
        a[4] = f2bf(x1.x); a[5] = f2bf(x1.y); a[6] = f2bf(x1.z); a[7] = f2bf(x1.w);
        afr[mt][cc] = a;
      }
    }
    __syncthreads();  // weights+gi visible; prev chunk's attB/gi reads done

    // ---- GEMM1: [32 nodes x 64 j], K=128
    f32x4 acc[2][4];
#pragma unroll
    for (int mt = 0; mt < 2; ++mt)
#pragma unroll
      for (int nt = 0; nt < 4; ++nt) acc[mt][nt] = (f32x4){0.f, 0.f, 0.f, 0.f};
#pragma unroll
    for (int cc = 0; cc < 4; ++cc) {
#pragma unroll
      for (int nt = 0; nt < 4; ++nt) {
        short8 bfr = *(const short8*)&W1T[nt * 16 + lr][cc * 32 + lq * 8];
        acc[0][nt] = __builtin_amdgcn_mfma_f32_16x16x32_bf16(afr[0][cc], bfr, acc[0][nt], 0, 0, 0);
        acc[1][nt] = __builtin_amdgcn_mfma_f32_16x16x32_bf16(afr[1][cc], bfr, acc[1][nt], 0, 0, 0);
      }
    }

    // ---- bias + leaky + LN over j(64); h -> hb bf16
#pragma unroll
    for (int mt = 0; mt < 2; ++mt) {
#pragma unroll
      for (int r = 0; r < 4; ++r) {
        float x[4], sa = 0.f, sb = 0.f;
#pragma unroll
        for (int nt = 0; nt < 4; ++nt) {
          float xvv = leaky(acc[mt][nt][r] + b1v[nt]);
          x[nt] = xvv; sa += xvv; sb = fmaf(xvv, xvv, sb);
        }
#pragma unroll
        for (int off = 1; off < 16; off <<= 1) {
          sa += __shfl_xor(sa, off);
          sb += __shfl_xor(sb, off);
        }
        float mu = sa * (1.f / M1);
        float var = sb * (1.f / M1) - mu * mu;
        float inv = rsqrtf(var + EPS);
        int node = w * 32 + mt * 16 + lq * 4 + r;
#pragma unroll
        for (int nt = 0; nt < 4; ++nt)
          hb[node][nt * 16 + lr] = f2bf((x[nt] - mu) * inv * g1v[nt] + btv[nt]);
      }
    }
    __syncthreads();

    // ---- GEMM2: att logits [32 nodes x 8 heads], K=64
    f32x4 acc2[2];
    acc2[0] = (f32x4){0.f, 0.f, 0.f, 0.f};
    acc2[1] = (f32x4){0.f, 0.f, 0.f, 0.f};
#pragma unroll
    for (int c2 = 0; c2 < 2; ++c2) {
      short8 bfr2 = *(const short8*)&W2T[lr][c2 * 32 + lq * 8];
#pragma unroll
      for (int mt = 0; mt < 2; ++mt) {
        short8 af2 = *(const short8*)&hb[w * 32 + mt * 16 + lr][c2 * 32 + lq * 8];
        acc2[mt] = __builtin_amdgcn_mfma_f32_16x16x32_bf16(af2, bfr2, acc2[mt], 0, 0, 0);
      }
    }
    __syncthreads();  // hb reads done -> attB overlay writable

    int gl_lo = gi[0];
    int gl_hi = gi[nvalid - 1];

    // ---- att = exp(.): attB[h][node] bf16; segment sums -> sL (LDS atomics)
    if (lr < NH) {
      float attv[2][4];
      int gnode[2][4];
#pragma unroll
      for (int mt = 0; mt < 2; ++mt)
#pragma unroll
        for (int r = 0; r < 4; ++r) {
          int node = w * 32 + mt * 16 + lq * 4 + r;
          float av = bf2f(f2bf(expf(acc2[mt][r] + b2v)));  // rounded value
          attv[mt][r] = av;
          gnode[mt][r] = gi[node];
          attB[lr][node] = f2bf(av);
        }
      for (int g = gl_lo; g <= gl_hi; ++g) {
        float ss = 0.f;
#pragma unroll
        for (int mt = 0; mt < 2; ++mt)
#pragma unroll
          for (int r = 0; r < 4; ++r)
            ss += (gnode[mt][r] == g) ? attv[mt][r] : 0.f;
        ss += __shfl_xor(ss, 16);
        ss += __shfl_xor(ss, 32);
        if (lq == 0) atomicAdd(&sL[g][lr], ss);
      }
    }
    __syncthreads();  // attB ready

    // ---- B-frags feat^T (L1/L2-hot re-read of this chunk)
    int dA = w * 32 + lr, dB = dA + 16;
    short8 bfA[4], bfB[4];
#pragma unroll
    for (int kc = 0; kc < 4; ++kc) {
      short8 ba, bb;
#pragma unroll
      for (int j = 0; j < 8; ++j) {
        int node = base + kc * 32 + lq * 8 + j;
        node = node < NN ? node : NN - 1;
        const float* fp = feat + (size_t)node * D;
        ba[j] = f2bf(fp[dA]);
        bb[j] = f2bf(fp[dB]);
      }
      bfA[kc] = ba;
      bfB[kc] = bb;
    }

    // ---- windowed aggregation MFMA; accumulate into LDS agg (race-free:
    // element (gi,h,d) maps to a unique thread within a chunk; chunks are
    // barrier-separated)
    int hA = lr & 7;
    for (int gp = gl_lo; gp <= gl_hi; gp += 4) {
      int t0 = gp + (lr >> 3);
      int t1 = t0 + 2;
      f32x4 c00 = (f32x4){0.f, 0.f, 0.f, 0.f};
      f32x4 c01 = (f32x4){0.f, 0.f, 0.f, 0.f};
      f32x4 c10 = (f32x4){0.f, 0.f, 0.f, 0.f};
      f32x4 c11 = (f32x4){0.f, 0.f, 0.f, 0.f};
#pragma unroll
      for (int kc = 0; kc < 4; ++kc) {
        short8 av = *(const short8*)&attB[hA][kc * 32 + lq * 8];
        uchar8 gv = *(const uchar8*)&gi[kc * 32 + lq * 8];
        short8 a0, a1;
#pragma unroll
        for (int j = 0; j < 8; ++j) {
          short x = av[j];
          a0[j] = (gv[j] == t0) ? x : (short)0;
          a1[j] = (gv[j] == t1) ? x : (short)0;
        }
        c00 = __builtin_amdgcn_mfma_f32_16x16x32_bf16(a0, bfA[kc], c00, 0, 0, 0);
        c01 = __builtin_amdgcn_mfma_f32_16x16x32_bf16(a0, bfB[kc], c01, 0, 0, 0);
        c10 = __builtin_amdgcn_mfma_f32_16x16x32_bf16(a1, bfA[kc], c10, 0, 0, 0);
        c11 = __builtin_amdgcn_mfma_f32_16x16x32_bf16(a1, bfB[kc], c11, 0, 0, 0);
      }
      int giC0 = gp + (lq >> 1);
      int giC1 = giC0 + 2;
      int hC = (lq & 1) * 4;
      if (giC0 < GPB) {
#pragma unroll
        for (int r = 0; r < 4; ++r) {
          agg[giC0][hC + r][dA] += c00[r];
          agg[giC0][hC + r][dB] += c01[r];
        }
      }
      if (giC1 < GPB) {
#pragma unroll
        for (int r = 0; r < 4; ++r) {
          agg[giC1][hC + r][dA] += c10[r];
          agg[giC1][hC + r][dB] += c11[r];
        }
      }
    }
  }
  __syncthreads();  // agg/sL final; attB reads done

  // ---- invs in place
  if (t < GPB * NH) {
    float sv = (&sL[0][0])[t];
    (&sL[0][0])[t] = sv > 0.f ? 1.f / sv : 0.f;
  }
  __syncthreads();

  // ---- aL[gi][h*128+d] = bf16(agg * invs)  (overlays hb; stride 1040 ->
  // rows 8 banks apart, conflict-free A-frag reads)
  for (int i = t; i < GPB * NH * D; i += 256) {
    int gi2 = i >> 10;
    int k = i & 1023;
    int h = k >> 7, d = k & 127;
    aL[gi2][k] = f2bf(agg[gi2][h][d] * sL[gi2][h]);
  }
  __syncthreads();

  // ---- W3 GEMM: [8 graphs x 128], K=1024 (rows 8..15 = duplicates, discarded)
  int ar = lr & 7;
  f32x4 acc3[2];
  acc3[0] = (f32x4){0.f, 0.f, 0.f, 0.f};
  acc3[1] = (f32x4){0.f, 0.f, 0.f, 0.f};
#pragma unroll
  for (int kc = 0; kc < 32; ++kc) {
    short8 a = *(const short8*)&aL[ar][kc * 32 + lq * 8];
#pragma unroll
    for (int nt = 0; nt < 2; ++nt) {
      int ncol = w * 32 + nt * 16 + lr;
      short8 b = *(const short8*)(W3T + (size_t)ncol * 1024 + kc * 32 + lq * 8);
      acc3[nt] = __builtin_amdgcn_mfma_f32_16x16x32_bf16(a, b, acc3[nt], 0, 0, 0);
    }
  }

  // ---- bias + leaky + LN(128) -> hbuf2 (4-wave reduction via red)
  float xv[2][4], sa[4] = {0.f, 0.f, 0.f, 0.f}, sb[4] = {0.f, 0.f, 0.f, 0.f};
#pragma unroll
  for (int nt = 0; nt < 2; ++nt) {
    float bb = b3[w * 32 + nt * 16 + lr];
#pragma unroll
    for (int r = 0; r < 4; ++r) {
      float v = leaky(acc3[nt][r] + bb);
      xv[nt][r] = v;
      sa[r] += v;
      sb[r] = fmaf(v, v, sb[r]);
    }
  }
#pragma unroll
  for (int off = 1; off < 16; off <<= 1)
#pragma unroll
    for (int r = 0; r < 4; ++r) {
      sa[r] += __shfl_xor(sa[r], off);
      sb[r] += __shfl_xor(sb[r], off);
    }
  if (lr == 0)
#pragma unroll
    for (int r = 0; r < 4; ++r) {
      red[w][0][lq * 4 + r] = sa[r];
      red[w][1][lq * 4 + r] = sb[r];
    }
  __syncthreads();
#pragma unroll
  for (int nt = 0; nt < 2; ++nt) {
    int col = w * 32 + nt * 16 + lr;
    float gg = g3[col], bt = beta3[col];
#pragma unroll
    for (int r = 0; r < 4; ++r) {
      int row = lq * 4 + r;
      float S1 = red[0][0][row] + red[1][0][row] + red[2][0][row] + red[3][0][row];
      float S2 = red[0][1][row] + red[1][1][row] + red[2][1][row] + red[3][1][row];
      float mu = S1 * (1.f / D);
      float var = S2 * (1.f / D) - mu * mu;
      float inv = rsqrtf(var + EPS);
      hbuf2[row][col] = f2bf((xv[nt][r] - mu) * inv * gg + bt);
    }
  }
  __syncthreads();

  // ---- W4 GEMM: [8 x 128], K=128
  f32x4 acc4[2];
  acc4[0] = (f32x4){0.f, 0.f, 0.f, 0.f};
  acc4[1] = (f32x4){0.f, 0.f, 0.f, 0.f};
#pragma unroll
  for (int kc = 0; kc < 4; ++kc) {
    short8 a2 = *(const short8*)&hbuf2[lr][kc * 32 + lq * 8];
#pragma unroll
    for (int nt = 0; nt < 2; ++nt) {
      int ncol = w * 32 + nt * 16 + lr;
      short8 b4f = *(const short8*)(W4T + (size_t)ncol * 128 + kc * 32 + lq * 8);
      acc4[nt] = __builtin_amdgcn_mfma_f32_16x16x32_bf16(a2, b4f, acc4[nt], 0, 0, 0);
    }
  }
#pragma unroll
  for (int r = 0; r < 4; ++r) { sa[r] = 0.f; sb[r] = 0.f; }
#pragma unroll
  for (int nt = 0; nt < 2; ++nt) {
    float bb = b4[w * 32 + nt * 16 + lr];
#pragma unroll
    for (int r = 0; r < 4; ++r) {
      float v = leaky(acc4[nt][r] + bb);
      xv[nt][r] = v;
      sa[r] += v;
      sb[r] = fmaf(v, v, sb[r]);
    }
  }
#pragma unroll
  for (int off = 1; off < 16; off <<= 1)
#pragma unroll
    for (int r = 0; r < 4; ++r) {
      sa[r] += __shfl_xor(sa[r], off);
      sb[r] += __shfl_xor(sb[r], off);
    }
  if (lr == 0)
#pragma unroll
    for (int r = 0; r < 4; ++r) {
      red[w][0][lq * 4 + r] = sa[r];
      red[w][1][lq * 4 + r] = sb[r];
    }
  __syncthreads();
#pragma unroll
  for (int nt = 0; nt < 2; ++nt) {
    int col = w * 32 + nt * 16 + lr;
    float gg = g4[col], bt = beta4[col];
#pragma unroll
    for (int r = 0; r < 4; ++r) {
      int row = lq * 4 + r;
      if (row < GPB) {
        float S1 = red[0][0][row] + red[1][0][row] + red[2][0][row] + red[3][0][row];
        float S2 = red[0][1][row] + red[1][1][row] + red[2][1][row] + red[3][1][row];
        float mu = S1 * (1.f / D);
        float var = S2 * (1.f / D) - mu * mu;
        float inv = rsqrtf(var + EPS);
        out[(size_t)(G0 + row) * D + col] = (xv[nt][r] - mu) * inv * gg + bt;
      }
    }
  }
}

extern "C" void kernel_launch(void* const* d_in, const int* in_sizes, int n_in,
                              void* d_out, int out_size, void* d_ws, size_t ws_size,
                              hipStream_t stream) {
  (void)in_sizes; (void)n_in; (void)out_size; (void)ws_size;
  const float* feat  = (const float*)d_in[0];
  const int*   batch = (const int*)d_in[1];
  const float* W1    = (const float*)d_in[2];
  const float* b1    = (const float*)d_in[3];
  const float* g1    = (const float*)d_in[4];
  const float* beta1 = (const float*)d_in[5];
  const float* W2    = (const float*)d_in[6];
  const float* b2    = (const float*)d_in[7];
  const float* W3    = (const float*)d_in[8];
  const float* b3    = (const float*)d_in[9];
  const float* g3    = (const float*)d_in[10];
  const float* beta3 = (const float*)d_in[11];
  const float* W4    = (const float*)d_in[12];
  const float* b4    = (const float*)d_in[13];
  const float* g4    = (const float*)d_in[14];
  const float* beta4 = (const float*)d_in[15];
  float* out = (float*)d_out;

  char* ws = (char*)d_ws;
  short* W3T   = (short*)ws;                        // 256 KB
  short* W4T   = (short*)(ws + 262144);             // 32 KB
  int*  starts = (int*)(ws + 262144 + 32768);       // (NG+1)*4 B

  k0b_prep<<<52, 256, 0, stream>>>(W3, W4, batch, W3T, W4T, starts);
  k_fused<<<NG / GPB, 256, 0, stream>>>(feat, batch, starts, W1, b1, g1, beta1,
                                        W2, b2, W3T, b3, g3, beta3, W4T, b4, g4,
                                        beta4, out);
}